// Round 15
// baseline (782.754 us; speedup 1.0000x reference)
//
#include <hip/hip_runtime.h>
#include <hip/hip_bf16.h>

// Problem constants
#define CN1 262144
#define CN2 65536
#define CPREV 512
#define CSKIP 256

using u16 = unsigned short;

typedef __attribute__((ext_vector_type(8))) short short8;
typedef __attribute__((ext_vector_type(8))) unsigned short ushort8;
typedef __attribute__((ext_vector_type(4))) float f32x4;
typedef __attribute__((ext_vector_type(8))) float f32x8;

__device__ __forceinline__ float toF(float v) { return v; }
__device__ __forceinline__ float toF(u16 u) { return __uint_as_float(((unsigned)u) << 16); }
__device__ __forceinline__ u16 f2bf(float f) {
    unsigned b = __float_as_uint(f);
    b += 0x7FFFu + ((b >> 16) & 1u);
    return (u16)(b >> 16);
}
__device__ __forceinline__ unsigned pack2(float lo, float hi) {
    return ((unsigned)f2bf(hi) << 16) | (unsigned)f2bf(lo);
}

// ---------------------------------------------------------------------------
// All three weight transposes in one launch: Wt[n][k] (bf16) = W[k][n] (f32).
// ---------------------------------------------------------------------------
__global__ __launch_bounds__(256) void transpose_all(
    const float* __restrict__ Wf0, const float* __restrict__ Ws0,
    const float* __restrict__ W1,
    u16* __restrict__ Wtf0, u16* __restrict__ Wts0, u16* __restrict__ Wt1)
{
    int b = blockIdx.x;
    const float* W; u16* Wt; int ksh, e;
    if (b < 512)      { W = Wf0; Wt = Wtf0; ksh = 9; e = b * 256 + threadIdx.x; }
    else if (b < 768) { W = Ws0; Wt = Wts0; ksh = 8; e = (b - 512) * 256 + threadIdx.x; }
    else              { W = W1;  Wt = Wt1;  ksh = 8; e = (b - 768) * 256 + threadIdx.x; }
    int K = 1 << ksh;
    int n = e >> ksh;
    int k = e & (K - 1);
    Wt[e] = f2bf(W[((size_t)k << 8) + n]);
}

// ---------------------------------------------------------------------------
// 8-wave epilogue (tile 128x256, wave grid 2x4, wave tile 64x64, acc[4][4]):
// (1) column-stat partials from acc (cs in Ax), (2) coalesced C store via
// per-wave patch in Bs (2304 B/wave; bf16: full 128-B line per 4 lanes).
// ---------------------------------------------------------------------------
template<typename OT>
__device__ __forceinline__ void epilogue8(
    f32x4 (&acc)[4][4], u16* Ax, u16* Bs,
    const float* __restrict__ bias, OT* __restrict__ C,
    float* __restrict__ partial, int bm, int t)
{
    const int lane = t & 63;
    const int wid = t >> 6;
    const int wrow = wid >> 2;
    const int wcol = wid & 3;
    __syncthreads();   // all fragment reads complete; LDS reusable
    float* cs  = (float*)Ax;           // [2][256] col sums
    float* cs2 = ((float*)Ax) + 512;   // [2][256] col sumsq (4 KB total)
    const int r4 = (lane >> 4) * 4;
    const int cc = lane & 15;
    float bv[4];
#pragma unroll
    for (int ni = 0; ni < 4; ++ni) bv[ni] = bias[wcol * 64 + ni * 16 + cc];

    // 1) column stats from accumulators
#pragma unroll
    for (int ni = 0; ni < 4; ++ni) {
        int col = wcol * 64 + ni * 16 + cc;
        float s = 0.f, s2 = 0.f;
#pragma unroll
        for (int mi = 0; mi < 4; ++mi) {
#pragma unroll
            for (int j = 0; j < 4; ++j) {
                float val = acc[mi][ni][j] + bv[ni];
                s += val;
                s2 = fmaf(val, val, s2);
            }
        }
        s  += __shfl_xor(s, 16);  s  += __shfl_xor(s, 32);
        s2 += __shfl_xor(s2, 16); s2 += __shfl_xor(s2, 32);
        if (lane < 16) { cs[wrow * 256 + col] = s; cs2[wrow * 256 + col] = s2; }
    }

    // 2) coalesced C store via per-wave patch in Bs (no overlap with cs)
    if constexpr (sizeof(OT) == 2) {
        u16* patchw = Bs + wid * 1152;
        const int trow = lane >> 2;
        const int c16 = (lane & 3) * 16;
#pragma unroll
        for (int mi = 0; mi < 4; ++mi) {
            __syncthreads();
#pragma unroll
            for (int ni = 0; ni < 4; ++ni)
#pragma unroll
                for (int j = 0; j < 4; ++j)
                    patchw[(r4 + j) * 72 + ni * 16 + cc] = f2bf(acc[mi][ni][j] + bv[ni]);
            __syncthreads();
            ushort8 u0 = *(const ushort8*)&patchw[trow * 72 + c16];
            ushort8 u1 = *(const ushort8*)&patchw[trow * 72 + c16 + 8];
            size_t r = (size_t)bm + wrow * 64 + mi * 16 + trow;
            size_t cb = (size_t)wcol * 64 + c16;
            *(ushort8*)((u16*)C + r * 256 + cb) = u0;
            *(ushort8*)((u16*)C + r * 256 + cb + 8) = u1;
        }
    } else {
        float* patchf = (float*)(Bs + wid * 1152);
        const int trow = lane >> 2;
        const int c8 = (lane & 3) * 8;
#pragma unroll
        for (int mi = 0; mi < 4; ++mi) {
#pragma unroll
            for (int np = 0; np < 2; ++np) {
                __syncthreads();
#pragma unroll
                for (int h = 0; h < 2; ++h) {
                    int ni = np * 2 + h;
#pragma unroll
                    for (int j = 0; j < 4; ++j)
                        patchf[(r4 + j) * 36 + h * 16 + cc] = acc[mi][ni][j] + bv[ni];
                }
                __syncthreads();
                float4 v0 = *(float4*)&patchf[trow * 36 + c8];
                float4 v1 = *(float4*)&patchf[trow * 36 + c8 + 4];
                size_t r = (size_t)bm + wrow * 64 + mi * 16 + trow;
                size_t cb = (size_t)wcol * 64 + np * 32 + c8;
                *(float4*)((float*)C + r * 256 + cb) = v0;
                *(float4*)((float*)C + r * 256 + cb + 4) = v1;
            }
        }
    }
    __syncthreads();
    if (t < 256) {
        partial[(size_t)blockIdx.x * 512 + t]       = cs[t] + cs[256 + t];
        partial[(size_t)blockIdx.x * 512 + 256 + t] = cs2[t] + cs2[256 + t];
    }
}

// ---------------------------------------------------------------------------
// MFMA GEMM, batched-A: per 256-wide K-half, Phase1 stages the ENTIRE A
// half-tile [128][256] f32->bf16 into LDS in one burst (latencies overlap),
// then Phase2 runs the 8-step K-loop gather-free (only B staged per step).
// Tile 128x256, 512 thr / 8 waves (2x4), wave tile 64x64.
// ---------------------------------------------------------------------------
template<int K, typename OT>
__global__ __launch_bounds__(512) void gemm_mfma(
    const float* __restrict__ Af, const u16* __restrict__ Wt,
    const float* __restrict__ bias, OT* __restrict__ C,
    float* __restrict__ partial)
{
    __shared__ u16 Ax[128 * 264];   // 67.6 KB, pitch 264 -> 2-way banks (free)
    __shared__ u16 Bs[256 * 40];    // 20 KB
    const int t = threadIdx.x;
    const int bm = blockIdx.x * 128;
    const int lane = t & 63;
    const int wid = t >> 6;
    const int wrow = wid >> 2;
    const int wcol = wid & 3;

    const int arow = t >> 2;        // 0..127
    const int q4 = t & 3;           // col quarter (64 cols each)
    const int brow = t >> 1;        // 0..255
    const int bko = (t & 1) * 16;
    const int rr = lane & 15;
    const int kq = (lane >> 4) * 8;

    f32x4 acc[4][4] = {};
    ushort8 gb0, gb1;

    auto LOADB = [&](int k0) {
        const u16* q = Wt + (size_t)brow * K + k0 + bko;
        gb0 = *(const ushort8*)q;
        gb1 = *(const ushort8*)(q + 8);
    };
    auto STAGEB = [&]() {
        *(ushort8*)&Bs[brow * 40 + bko] = gb0;
        *(ushort8*)&Bs[brow * 40 + bko + 8] = gb1;
    };
    auto MMA = [&](int it) {
        short8 af[4];
#pragma unroll
        for (int mi = 0; mi < 4; ++mi)
            af[mi] = *(const short8*)&Ax[(wrow * 64 + mi * 16 + rr) * 264 + it * 32 + kq];
#pragma unroll
        for (int ni = 0; ni < 4; ++ni) {
            short8 bf = *(const short8*)&Bs[(wcol * 64 + ni * 16 + rr) * 40 + kq];
#pragma unroll
            for (int mi = 0; mi < 4; ++mi)
                acc[mi][ni] = __builtin_amdgcn_mfma_f32_16x16x32_bf16(
                    af[mi], bf, acc[mi][ni], 0, 0, 0);
        }
    };

#pragma unroll
    for (int h = 0; h < K / 256; ++h) {
        __syncthreads();            // previous half's MMA reads of Ax done
        {   // Phase 1: batch-stage the A half-tile (32 indep 16B-loads/thread)
            const float* base = Af + (size_t)(bm + arow) * K + h * 256 + q4 * 64;
#pragma unroll
            for (int c = 0; c < 8; ++c) {
                float4 f0 = *(const float4*)(base + c * 8);
                float4 f1 = *(const float4*)(base + c * 8 + 4);
                uint4 w;
                w.x = pack2(f0.x, f0.y); w.y = pack2(f0.z, f0.w);
                w.z = pack2(f1.x, f1.y); w.w = pack2(f1.z, f1.w);
                *(uint4*)&Ax[arow * 264 + q4 * 64 + c * 8] = w;
            }
        }
        LOADB(h * 256);
        // Phase 2: gather-free K-loop (B staged per step)
        for (int it = 0; it < 8; ++it) {
            __syncthreads();        // Ax visible (it=0) / Bs reads done
            STAGEB();
            __syncthreads();        // Bs visible
            if (it + 1 < 8) LOADB(h * 256 + (it + 1) * 32);
            MMA(it);
        }
    }

    epilogue8<OT>(acc, Ax, Bs, bias, C, partial, bm, t);
}

// ---------------------------------------------------------------------------
// Fused GEMM for layer 1, batched-A: Phase1 gathers each y2/skip row ONCE
// (full 512 B), computes x = relu(interp*sf + skip*sx + csh), stages [128][256]
// bf16 to LDS. Phase2: gather-free 8-step K-loop. K=256.
// ---------------------------------------------------------------------------
template<typename OT>
__global__ __launch_bounds__(512) void gemm_fused(
    const u16* __restrict__ skipb, const u16* __restrict__ y2,
    const float* __restrict__ dist, const int* __restrict__ idx,
    const float* __restrict__ ssf, const float* __restrict__ sss,
    const u16* __restrict__ Wt, const float* __restrict__ bias,
    OT* __restrict__ C, float* __restrict__ partial)
{
    constexpr int K = 256;
    __shared__ u16 Ax[128 * 264];
    __shared__ u16 Bs[256 * 40];
    __shared__ float sstab[768];    // scale_f0 | scale_s0 | shift(folded)
    const int t = threadIdx.x;
    const int bm = blockIdx.x * 128;
    const int lane = t & 63;
    const int wid = t >> 6;
    const int wrow = wid >> 2;
    const int wcol = wid & 3;

    const int arow = t >> 2;        // 0..127
    const int q4 = t & 3;
    const int brow = t >> 1;
    const int bko = (t & 1) * 16;
    const int rr = lane & 15;
    const int kq = (lane >> 4) * 8;
    const int row = bm + arow;

    for (int e = t; e < 768; e += 512)
        sstab[e] = (e < 256) ? ssf[e] : sss[e - 256];

    float d0 = dist[row * 3 + 0], d1 = dist[row * 3 + 1], d2 = dist[row * 3 + 2];
    float r0 = 1.f / (d0 + 1e-8f), r1 = 1.f / (d1 + 1e-8f), r2 = 1.f / (d2 + 1e-8f);
    float inv = 1.f / (r0 + r1 + r2);
    const float w0 = r0 * inv, w1 = r1 * inv, w2 = r2 * inv;
    const unsigned i0 = (unsigned)idx[row * 3 + 0];
    const unsigned i1 = (unsigned)idx[row * 3 + 1];
    const unsigned i2 = (unsigned)idx[row * 3 + 2];

    f32x4 acc[4][4] = {};
    ushort8 gb0, gb1;

    auto LOADB = [&](int k0) {
        const u16* q = Wt + (size_t)brow * K + k0 + bko;
        gb0 = *(const ushort8*)q;
        gb1 = *(const ushort8*)(q + 8);
    };
    auto STAGEB = [&]() {
        *(ushort8*)&Bs[brow * 40 + bko] = gb0;
        *(ushort8*)&Bs[brow * 40 + bko + 8] = gb1;
    };
    auto MMA = [&](int it) {
        short8 af[4];
#pragma unroll
        for (int mi = 0; mi < 4; ++mi)
            af[mi] = *(const short8*)&Ax[(wrow * 64 + mi * 16 + rr) * 264 + it * 32 + kq];
#pragma unroll
        for (int ni = 0; ni < 4; ++ni) {
            short8 bf = *(const short8*)&Bs[(wcol * 64 + ni * 16 + rr) * 40 + kq];
#pragma unroll
            for (int mi = 0; mi < 4; ++mi)
                acc[mi][ni] = __builtin_amdgcn_mfma_f32_16x16x32_bf16(
                    af[mi], bf, acc[mi][ni], 0, 0, 0);
        }
    };

    __syncthreads();                // sstab visible before Phase 1
    {   // Phase 1: batch gather + interp + BN + relu -> Ax
#pragma unroll
        for (int c = 0; c < 8; ++c) {
            const int kc = q4 * 64 + c * 8;
            ushort8 sk = *(const ushort8*)(skipb + (size_t)row * 256 + kc);
            ushort8 a0 = *(const ushort8*)(y2 + (size_t)i0 * 256 + kc);
            ushort8 a1 = *(const ushort8*)(y2 + (size_t)i1 * 256 + kc);
            ushort8 a2 = *(const ushort8*)(y2 + (size_t)i2 * 256 + kc);
            f32x8 sf = *(const f32x8*)&sstab[kc];
            f32x8 sx = *(const f32x8*)&sstab[256 + kc];
            f32x8 ch = *(const f32x8*)&sstab[512 + kc];
            float xs[8];
#pragma unroll
            for (int j = 0; j < 8; ++j) {
                float iv = w0 * toF((u16)a0[j]) + w1 * toF((u16)a1[j])
                         + w2 * toF((u16)a2[j]);
                float val = fmaf(iv, sf[j], fmaf(toF((u16)sk[j]), sx[j], ch[j]));
                xs[j] = fmaxf(val, 0.f);
            }
            uint4 w;
            w.x = pack2(xs[0], xs[1]);
            w.y = pack2(xs[2], xs[3]);
            w.z = pack2(xs[4], xs[5]);
            w.w = pack2(xs[6], xs[7]);
            *(uint4*)&Ax[arow * 264 + kc] = w;
        }
    }
    LOADB(0);
    for (int it = 0; it < 8; ++it) {
        __syncthreads();            // Ax visible (it=0) / Bs reads done
        STAGEB();
        __syncthreads();
        if (it + 1 < 8) LOADB((it + 1) * 32);
        MMA(it);
    }

    epilogue8<OT>(acc, Ax, Bs, bias, C, partial, bm, t);
}

// ---------------------------------------------------------------------------
// Stats finalize: one block per column; optional shift folding.
// ---------------------------------------------------------------------------
__global__ __launch_bounds__(256) void colstats_final_par(
    const float* __restrict__ partial, int nb, float invR,
    const float* __restrict__ g, const float* __restrict__ beta,
    const float* __restrict__ fold, float* __restrict__ ss)
{
    int c = blockIdx.x;
    int t = threadIdx.x;
    float s = 0.f, s2 = 0.f;
    for (int b = t; b < nb; b += 256) {
        s  += partial[(size_t)b * 512 + c];
        s2 += partial[(size_t)b * 512 + 256 + c];
    }
#pragma unroll
    for (int o = 32; o > 0; o >>= 1) {
        s += __shfl_xor(s, o);
        s2 += __shfl_xor(s2, o);
    }
    __shared__ float rs[4], rs2[4];
    if ((t & 63) == 0) { rs[t >> 6] = s; rs2[t >> 6] = s2; }
    __syncthreads();
    if (t == 0) {
        float S  = rs[0] + rs[1] + rs[2] + rs[3];
        float S2 = rs2[0] + rs2[1] + rs2[2] + rs2[3];
        float m = S * invR;
        float var = fmaf(-m, m, S2 * invR);
        float scale = g[c] * rsqrtf(var + 1e-5f);
        float shift = fmaf(-m, scale, beta[c]);
        if (fold) shift += fold[256 + c];
        ss[c] = scale;
        ss[256 + c] = shift;
    }
}

// ---------------------------------------------------------------------------
// out(f32) = relu(y3(bf16) * scale + shift)
// ---------------------------------------------------------------------------
__global__ __launch_bounds__(256) void bn_relu_cvt(
    const u16* __restrict__ y3, float* __restrict__ out,
    const float* __restrict__ ss)
{
    size_t e = ((size_t)blockIdx.x * 256 + threadIdx.x) * 8;
    int kc = (int)(e & 255);
    ushort8 v = *(const ushort8*)(y3 + e);
    f32x8 sc = *(const f32x8*)(ss + kc);
    f32x8 sh = *(const f32x8*)(ss + 256 + kc);
    float4 o0, o1;
    o0.x = fmaxf(fmaf(toF((u16)v[0]), sc[0], sh[0]), 0.f);
    o0.y = fmaxf(fmaf(toF((u16)v[1]), sc[1], sh[1]), 0.f);
    o0.z = fmaxf(fmaf(toF((u16)v[2]), sc[2], sh[2]), 0.f);
    o0.w = fmaxf(fmaf(toF((u16)v[3]), sc[3], sh[3]), 0.f);
    o1.x = fmaxf(fmaf(toF((u16)v[4]), sc[4], sh[4]), 0.f);
    o1.y = fmaxf(fmaf(toF((u16)v[5]), sc[5], sh[5]), 0.f);
    o1.z = fmaxf(fmaf(toF((u16)v[6]), sc[6], sh[6]), 0.f);
    o1.w = fmaxf(fmaf(toF((u16)v[7]), sc[7], sh[7]), 0.f);
    *(float4*)(out + e) = o0;
    *(float4*)(out + e + 4) = o1;
}

// ---------------------------------------------------------------------------
// out = relu(out * scale + shift), in place (fallback when ws too small)
// ---------------------------------------------------------------------------
__global__ __launch_bounds__(256) void bn_relu_inplace(
    float* __restrict__ out, const float* __restrict__ ss)
{
    size_t i4 = (size_t)blockIdx.x * 256 + threadIdx.x;
    int c4 = (int)(i4 & 63);
    float4 v = reinterpret_cast<float4*>(out)[i4];
    float4 sc = reinterpret_cast<const float4*>(ss)[c4];
    float4 sh = reinterpret_cast<const float4*>(ss + 256)[c4];
    v.x = fmaxf(fmaf(v.x, sc.x, sh.x), 0.f);
    v.y = fmaxf(fmaf(v.y, sc.y, sh.y), 0.f);
    v.z = fmaxf(fmaf(v.z, sc.z, sh.z), 0.f);
    v.w = fmaxf(fmaf(v.w, sc.w, sh.w), 0.f);
    reinterpret_cast<float4*>(out)[i4] = v;
}

// ---------------------------------------------------------------------------
extern "C" void kernel_launch(void* const* d_in, const int* in_sizes, int n_in,
                              void* d_out, int out_size, void* d_ws, size_t ws_size,
                              hipStream_t stream) {
    const float* points1 = (const float*)d_in[0];
    const float* points2 = (const float*)d_in[1];
    const float* dist    = (const float*)d_in[2];
    const int*   idx     = (const int*)d_in[3];
    const float* Wf0     = (const float*)d_in[4];
    const float* bf0     = (const float*)d_in[5];
    const float* gf0     = (const float*)d_in[6];
    const float* betaf0  = (const float*)d_in[7];
    const float* Ws0     = (const float*)d_in[8];
    const float* bs0     = (const float*)d_in[9];
    const float* gs0     = (const float*)d_in[10];
    const float* betas0  = (const float*)d_in[11];
    const float* W1      = (const float*)d_in[12];
    const float* b1      = (const float*)d_in[13];
    const float* g1      = (const float*)d_in[14];
    const float* beta1   = (const float*)d_in[15];

    u16* ws = (u16*)d_ws;
    size_t off = 0;
    u16* y2   = ws + off;  off += (size_t)CN2 * 256;   // 32MB
    u16* xbuf = ws + off;  off += (size_t)CN1 * 256;   // 128MB
    u16* Wtf0 = ws + off;  off += 512 * 256;
    u16* Wts0 = ws + off;  off += 256 * 256;
    u16* Wt1  = ws + off;  off += 256 * 256;
    float* partial = (float*)(ws + off); off += (size_t)2048 * 512 * 2;  // 4MB
    float* ss_f0 = (float*)(ws + off); off += 1024;
    float* ss_s0 = (float*)(ws + off); off += 1024;
    float* ss_1  = (float*)(ws + off); off += 1024;
    u16* y3 = ws + off;
    const size_t NEED = (off + (size_t)CN1 * 256) * 2;   // bytes incl. bf16 y3
    const bool fused_y3 = (ws_size >= NEED);
    float* out = (float*)d_out;

    // weight transposes (f32 -> bf16, [K][256] -> [256][K]) in one launch
    transpose_all<<<1024, 256, 0, stream>>>(Wf0, Ws0, W1, Wtf0, Wts0, Wt1);

    // 1) y2 = points2 @ Wf0 + bf0   [N2 x 256] bf16, + col partials
    gemm_mfma<512, u16><<<CN2 / 128, 512, 0, stream>>>(
        points2, Wtf0, bf0, y2, partial);
    colstats_final_par<<<256, 256, 0, stream>>>(partial, CN2 / 128, 1.0f / CN2,
                                                gf0, betaf0, nullptr, ss_f0);
    // 2) skip_pre = points1 @ Ws0 + bs0   [N1 x 256] bf16, + col partials
    gemm_mfma<256, u16><<<CN1 / 128, 512, 0, stream>>>(
        points1, Wts0, bs0, xbuf, partial);
    // fold f0 shift into s0 shift (interp identity: sum w = 1)
    colstats_final_par<<<256, 256, 0, stream>>>(partial, CN1 / 128, 1.0f / CN1,
                                                gs0, betas0, ss_f0, ss_s0);
    // 3) y3 = relu(interp+skip) @ W1 + b1 (interp fused into Phase-1 staging)
    if (fused_y3) {
        gemm_fused<u16><<<CN1 / 128, 512, 0, stream>>>(
            xbuf, y2, dist, idx, ss_f0, ss_s0, Wt1, b1, y3, partial);
    } else {
        gemm_fused<float><<<CN1 / 128, 512, 0, stream>>>(
            xbuf, y2, dist, idx, ss_f0, ss_s0, Wt1, b1, out, partial);
    }
    colstats_final_par<<<256, 256, 0, stream>>>(partial, CN1 / 128, 1.0f / CN1,
                                                g1, beta1, nullptr, ss_1);
    // 4) out = relu(bn(y3))
    if (fused_y3) {
        bn_relu_cvt<<<32768, 256, 0, stream>>>(y3, out, ss_1);
    } else {
        bn_relu_inplace<<<CN1 / 4, 256, 0, stream>>>(out, ss_1);
    }
}

// Round 16
// 428.817 us; speedup vs baseline: 1.8254x; 1.8254x over previous
//
#include <hip/hip_runtime.h>
#include <hip/hip_bf16.h>

// Problem constants
#define CN1 262144
#define CN2 65536
#define CPREV 512
#define CSKIP 256

using u16 = unsigned short;

typedef __attribute__((ext_vector_type(8))) short short8;
typedef __attribute__((ext_vector_type(8))) unsigned short ushort8;
typedef __attribute__((ext_vector_type(4))) float f32x4;
typedef __attribute__((ext_vector_type(8))) float f32x8;

__device__ __forceinline__ float toF(float v) { return v; }
__device__ __forceinline__ float toF(u16 u) { return __uint_as_float(((unsigned)u) << 16); }
__device__ __forceinline__ u16 f2bf(float f) {
    unsigned b = __float_as_uint(f);
    b += 0x7FFFu + ((b >> 16) & 1u);
    return (u16)(b >> 16);
}
__device__ __forceinline__ unsigned pack2(float lo, float hi) {
    return ((unsigned)f2bf(hi) << 16) | (unsigned)f2bf(lo);
}

// ---------------------------------------------------------------------------
// All three weight transposes in one launch: Wt[n][k] (bf16) = W[k][n] (f32).
// ---------------------------------------------------------------------------
__global__ __launch_bounds__(256) void transpose_all(
    const float* __restrict__ Wf0, const float* __restrict__ Ws0,
    const float* __restrict__ W1,
    u16* __restrict__ Wtf0, u16* __restrict__ Wts0, u16* __restrict__ Wt1)
{
    int b = blockIdx.x;
    const float* W; u16* Wt; int ksh, e;
    if (b < 512)      { W = Wf0; Wt = Wtf0; ksh = 9; e = b * 256 + threadIdx.x; }
    else if (b < 768) { W = Ws0; Wt = Wts0; ksh = 8; e = (b - 512) * 256 + threadIdx.x; }
    else              { W = W1;  Wt = Wt1;  ksh = 8; e = (b - 768) * 256 + threadIdx.x; }
    int K = 1 << ksh;
    int n = e >> ksh;
    int k = e & (K - 1);
    Wt[e] = f2bf(W[((size_t)k << 8) + n]);
}

// ---------------------------------------------------------------------------
// 8-wave epilogue (tile 128x256, wave grid 2x4, wave tile 64x64, acc[4][4]):
// (1) column-stat partials from acc (cs in first LDS buf), (2) coalesced C
// store via per-wave patch in second buf (bf16: full 128-B line per 4 lanes).
// ---------------------------------------------------------------------------
template<typename OT>
__device__ __forceinline__ void epilogue8(
    f32x4 (&acc)[4][4], u16* CsU, u16* PatchU,
    const float* __restrict__ bias, OT* __restrict__ C,
    float* __restrict__ partial, int bm, int t)
{
    const int lane = t & 63;
    const int wid = t >> 6;
    const int wrow = wid >> 2;
    const int wcol = wid & 3;
    __syncthreads();   // all fragment reads complete; LDS reusable
    float* cs  = (float*)CsU;          // [2][256] col sums
    float* cs2 = ((float*)CsU) + 512;  // [2][256] col sumsq (4 KB total)
    const int r4 = (lane >> 4) * 4;
    const int cc = lane & 15;
    float bv[4];
#pragma unroll
    for (int ni = 0; ni < 4; ++ni) bv[ni] = bias[wcol * 64 + ni * 16 + cc];

    // 1) column stats from accumulators
#pragma unroll
    for (int ni = 0; ni < 4; ++ni) {
        int col = wcol * 64 + ni * 16 + cc;
        float s = 0.f, s2 = 0.f;
#pragma unroll
        for (int mi = 0; mi < 4; ++mi) {
#pragma unroll
            for (int j = 0; j < 4; ++j) {
                float val = acc[mi][ni][j] + bv[ni];
                s += val;
                s2 = fmaf(val, val, s2);
            }
        }
        s  += __shfl_xor(s, 16);  s  += __shfl_xor(s, 32);
        s2 += __shfl_xor(s2, 16); s2 += __shfl_xor(s2, 32);
        if (lane < 16) { cs[wrow * 256 + col] = s; cs2[wrow * 256 + col] = s2; }
    }

    // 2) coalesced C store via per-wave patch
    if constexpr (sizeof(OT) == 2) {
        u16* patchw = PatchU + wid * 1152;
        const int trow = lane >> 2;
        const int c16 = (lane & 3) * 16;
#pragma unroll
        for (int mi = 0; mi < 4; ++mi) {
            __syncthreads();
#pragma unroll
            for (int ni = 0; ni < 4; ++ni)
#pragma unroll
                for (int j = 0; j < 4; ++j)
                    patchw[(r4 + j) * 72 + ni * 16 + cc] = f2bf(acc[mi][ni][j] + bv[ni]);
            __syncthreads();
            ushort8 u0 = *(const ushort8*)&patchw[trow * 72 + c16];
            ushort8 u1 = *(const ushort8*)&patchw[trow * 72 + c16 + 8];
            size_t r = (size_t)bm + wrow * 64 + mi * 16 + trow;
            size_t cb = (size_t)wcol * 64 + c16;
            *(ushort8*)((u16*)C + r * 256 + cb) = u0;
            *(ushort8*)((u16*)C + r * 256 + cb + 8) = u1;
        }
    } else {
        float* patchf = (float*)(PatchU + wid * 1152);
        const int trow = lane >> 2;
        const int c8 = (lane & 3) * 8;
#pragma unroll
        for (int mi = 0; mi < 4; ++mi) {
#pragma unroll
            for (int np = 0; np < 2; ++np) {
                __syncthreads();
#pragma unroll
                for (int h = 0; h < 2; ++h) {
                    int ni = np * 2 + h;
#pragma unroll
                    for (int j = 0; j < 4; ++j)
                        patchf[(r4 + j) * 36 + h * 16 + cc] = acc[mi][ni][j] + bv[ni];
                }
                __syncthreads();
                float4 v0 = *(float4*)&patchf[trow * 36 + c8];
                float4 v1 = *(float4*)&patchf[trow * 36 + c8 + 4];
                size_t r = (size_t)bm + wrow * 64 + mi * 16 + trow;
                size_t cb = (size_t)wcol * 64 + np * 32 + c8;
                *(float4*)((float*)C + r * 256 + cb) = v0;
                *(float4*)((float*)C + r * 256 + cb + 4) = v1;
            }
        }
    }
    __syncthreads();
    if (t < 256) {
        partial[(size_t)blockIdx.x * 512 + t]       = cs[t] + cs[256 + t];
        partial[(size_t)blockIdx.x * 512 + 256 + t] = cs2[t] + cs2[256 + t];
    }
}

// ---------------------------------------------------------------------------
// MFMA GEMM (R9 structure, best measured): C[M x 256] = A[M x K] @ W + bias.
// A f32 converted during staging. BM=128, BN=256, BK=32. 512 thr / 8 waves.
// Single-buffer LDS, 2 barriers/step, named-reg depth-2 prefetch.
// ---------------------------------------------------------------------------
template<int K, typename OT>
__global__ __launch_bounds__(512) void gemm_mfma(
    const float* __restrict__ Af, const u16* __restrict__ Wt,
    const float* __restrict__ bias, OT* __restrict__ C,
    float* __restrict__ partial)
{
    __shared__ u16 As[128 * 40];
    __shared__ u16 Bs[256 * 40];
    const int t = threadIdx.x;
    const int bm = blockIdx.x * 128;
    const int lane = t & 63;
    const int wid = t >> 6;
    const int wrow = wid >> 2;
    const int wcol = wid & 3;

    const int arow = t >> 2;       // 0..127
    const int koff = (t & 3) * 8;  // 0,8,16,24

    f32x4 acc[4][4] = {};

    float4 ga0A, ga1A, ga0B, ga1B;
    ushort8 gb0A, gb1A, gb0B, gb1B;

    auto LOADA = [&](int k0) {
        const float* p = Af + (size_t)(bm + arow) * K + k0 + koff;
        ga0A = *(const float4*)p;
        ga1A = *(const float4*)(p + 4);
        const u16* q = Wt + (size_t)arow * K + k0 + koff;
        gb0A = *(const ushort8*)q;
        gb1A = *(const ushort8*)(q + (size_t)128 * K);
    };
    auto LOADB = [&](int k0) {
        const float* p = Af + (size_t)(bm + arow) * K + k0 + koff;
        ga0B = *(const float4*)p;
        ga1B = *(const float4*)(p + 4);
        const u16* q = Wt + (size_t)arow * K + k0 + koff;
        gb0B = *(const ushort8*)q;
        gb1B = *(const ushort8*)(q + (size_t)128 * K);
    };
    auto STAGE = [&](const float4& g0, const float4& g1,
                     const ushort8& b0, const ushort8& b1) {
        uint4 w;
        w.x = pack2(g0.x, g0.y);
        w.y = pack2(g0.z, g0.w);
        w.z = pack2(g1.x, g1.y);
        w.w = pack2(g1.z, g1.w);
        *(uint4*)&As[arow * 40 + koff] = w;
        *(ushort8*)&Bs[arow * 40 + koff] = b0;
        *(ushort8*)&Bs[(128 + arow) * 40 + koff] = b1;
    };
    auto MMA = [&]() {
        const int kq = (lane >> 4) * 8;
        const int rr = lane & 15;
        short8 af[4];
#pragma unroll
        for (int mi = 0; mi < 4; ++mi)
            af[mi] = *(const short8*)&As[(wrow * 64 + mi * 16 + rr) * 40 + kq];
#pragma unroll
        for (int ni = 0; ni < 4; ++ni) {
            short8 bf = *(const short8*)&Bs[(wcol * 64 + ni * 16 + rr) * 40 + kq];
#pragma unroll
            for (int mi = 0; mi < 4; ++mi)
                acc[mi][ni] = __builtin_amdgcn_mfma_f32_16x16x32_bf16(
                    af[mi], bf, acc[mi][ni], 0, 0, 0);
        }
    };

    constexpr int nk = K >> 5;   // even (16 or 8)
    LOADA(0);
    LOADB(32);
#pragma unroll
    for (int it = 0; it < nk; it += 2) {
        __syncthreads();
        STAGE(ga0A, ga1A, gb0A, gb1A);
        __syncthreads();
        if (it + 2 < nk) LOADA((it + 2) << 5);
        MMA();
        __syncthreads();
        STAGE(ga0B, ga1B, gb0B, gb1B);
        __syncthreads();
        if (it + 3 < nk) LOADB((it + 3) << 5);
        MMA();
    }

    epilogue8<OT>(acc, As, Bs, bias, C, partial, bm, t);
}

// ---------------------------------------------------------------------------
// Fused GEMM for layer 1, batched-A with ROW-PER-WAVE coalesced gather:
// Phase 1: wave w stages rows w*16..w*16+15; per row, all 64 lanes read
// ushort4 at lane*8 B -> one instruction = one full 512-B row (coalesced).
// x = relu(interp*sf + skip*sx + csh) -> Ax[128][264] bf16.
// Phase 2: gather-free 8-step K-loop (B staged per step). K=256.
// ---------------------------------------------------------------------------
template<typename OT>
__global__ __launch_bounds__(512) void gemm_fused(
    const u16* __restrict__ skipb, const u16* __restrict__ y2,
    const float* __restrict__ dist, const int* __restrict__ idx,
    const float* __restrict__ ssf, const float* __restrict__ sss,
    const u16* __restrict__ Wt, const float* __restrict__ bias,
    OT* __restrict__ C, float* __restrict__ partial)
{
    constexpr int K = 256;
    __shared__ u16 Ax[128 * 264];   // 67.6 KB (pitch 264: 16B-aligned rows)
    __shared__ u16 Bs[256 * 40];    // 20 KB
    __shared__ float sstab[768];    // scale_f0 | scale_s0 | shift(folded)
    const int t = threadIdx.x;
    const int bm = blockIdx.x * 128;
    const int lane = t & 63;
    const int wid = t >> 6;
    const int wrow = wid >> 2;
    const int wcol = wid & 3;

    const int brow = t >> 1;        // B-stager row 0..255
    const int bko = (t & 1) * 16;
    const int rr = lane & 15;
    const int kq = (lane >> 4) * 8;

    for (int e = t; e < 768; e += 512)
        sstab[e] = (e < 256) ? ssf[e] : sss[e - 256];
    __syncthreads();                // sstab visible before Phase 1

    // per-lane column constants (row-independent)
    const int col4 = lane * 4;      // u16 column of this lane's 4 elements
    f32x4 sf = *(const f32x4*)&sstab[col4];
    f32x4 sx = *(const f32x4*)&sstab[256 + col4];
    f32x4 ch = *(const f32x4*)&sstab[512 + col4];

    f32x4 acc[4][4] = {};
    ushort8 gb0, gb1;

    auto LOADB = [&](int k0) {
        const u16* q = Wt + (size_t)brow * K + k0 + bko;
        gb0 = *(const ushort8*)q;
        gb1 = *(const ushort8*)(q + 8);
    };
    auto STAGEB = [&]() {
        *(ushort8*)&Bs[brow * 40 + bko] = gb0;
        *(ushort8*)&Bs[brow * 40 + bko + 8] = gb1;
    };
    auto MMA = [&](int it) {
        short8 af[4];
#pragma unroll
        for (int mi = 0; mi < 4; ++mi)
            af[mi] = *(const short8*)&Ax[(wrow * 64 + mi * 16 + rr) * 264 + it * 32 + kq];
#pragma unroll
        for (int ni = 0; ni < 4; ++ni) {
            short8 bf = *(const short8*)&Bs[(wcol * 64 + ni * 16 + rr) * 40 + kq];
#pragma unroll
            for (int mi = 0; mi < 4; ++mi)
                acc[mi][ni] = __builtin_amdgcn_mfma_f32_16x16x32_bf16(
                    af[mi], bf, acc[mi][ni], 0, 0, 0);
        }
    };

    // Phase 1: batched gather, row-per-wave, groups of 4 rows (16 loads in flight)
#pragma unroll
    for (int g = 0; g < 4; ++g) {
        ushort4 sk[4], a0[4], a1[4], a2[4];
        float w0[4], w1[4], w2[4];
#pragma unroll
        for (int u = 0; u < 4; ++u) {
            const int r = wid * 16 + g * 4 + u;
            const int row = bm + r;
            float d0 = dist[row * 3 + 0], d1 = dist[row * 3 + 1], d2 = dist[row * 3 + 2];
            float r0 = 1.f / (d0 + 1e-8f), r1 = 1.f / (d1 + 1e-8f), r2 = 1.f / (d2 + 1e-8f);
            float inv = 1.f / (r0 + r1 + r2);
            w0[u] = r0 * inv; w1[u] = r1 * inv; w2[u] = r2 * inv;
            const size_t i0 = (size_t)(unsigned)idx[row * 3 + 0];
            const size_t i1 = (size_t)(unsigned)idx[row * 3 + 1];
            const size_t i2 = (size_t)(unsigned)idx[row * 3 + 2];
            sk[u] = *(const ushort4*)(skipb + (size_t)row * 256 + col4);
            a0[u] = *(const ushort4*)(y2 + i0 * 256 + col4);
            a1[u] = *(const ushort4*)(y2 + i1 * 256 + col4);
            a2[u] = *(const ushort4*)(y2 + i2 * 256 + col4);
        }
#pragma unroll
        for (int u = 0; u < 4; ++u) {
            const int r = wid * 16 + g * 4 + u;
            float xs[4];
            {
                float iv = w0[u] * toF((u16)a0[u].x) + w1[u] * toF((u16)a1[u].x)
                         + w2[u] * toF((u16)a2[u].x);
                xs[0] = fmaxf(fmaf(iv, sf[0], fmaf(toF((u16)sk[u].x), sx[0], ch[0])), 0.f);
            }
            {
                float iv = w0[u] * toF((u16)a0[u].y) + w1[u] * toF((u16)a1[u].y)
                         + w2[u] * toF((u16)a2[u].y);
                xs[1] = fmaxf(fmaf(iv, sf[1], fmaf(toF((u16)sk[u].y), sx[1], ch[1])), 0.f);
            }
            {
                float iv = w0[u] * toF((u16)a0[u].z) + w1[u] * toF((u16)a1[u].z)
                         + w2[u] * toF((u16)a2[u].z);
                xs[2] = fmaxf(fmaf(iv, sf[2], fmaf(toF((u16)sk[u].z), sx[2], ch[2])), 0.f);
            }
            {
                float iv = w0[u] * toF((u16)a0[u].w) + w1[u] * toF((u16)a1[u].w)
                         + w2[u] * toF((u16)a2[u].w);
                xs[3] = fmaxf(fmaf(iv, sf[3], fmaf(toF((u16)sk[u].w), sx[3], ch[3])), 0.f);
            }
            uint2 wv;
            wv.x = pack2(xs[0], xs[1]);
            wv.y = pack2(xs[2], xs[3]);
            *(uint2*)&Ax[r * 264 + col4] = wv;
        }
    }

    LOADB(0);
    for (int it = 0; it < 8; ++it) {
        __syncthreads();            // Ax visible (it=0) / Bs reads done
        STAGEB();
        __syncthreads();
        if (it + 1 < 8) LOADB((it + 1) * 32);
        MMA(it);
    }

    epilogue8<OT>(acc, Ax, Bs, bias, C, partial, bm, t);
}

// ---------------------------------------------------------------------------
// Stats finalize: one block per column; optional shift folding.
// ---------------------------------------------------------------------------
__global__ __launch_bounds__(256) void colstats_final_par(
    const float* __restrict__ partial, int nb, float invR,
    const float* __restrict__ g, const float* __restrict__ beta,
    const float* __restrict__ fold, float* __restrict__ ss)
{
    int c = blockIdx.x;
    int t = threadIdx.x;
    float s = 0.f, s2 = 0.f;
    for (int b = t; b < nb; b += 256) {
        s  += partial[(size_t)b * 512 + c];
        s2 += partial[(size_t)b * 512 + 256 + c];
    }
#pragma unroll
    for (int o = 32; o > 0; o >>= 1) {
        s += __shfl_xor(s, o);
        s2 += __shfl_xor(s2, o);
    }
    __shared__ float rs[4], rs2[4];
    if ((t & 63) == 0) { rs[t >> 6] = s; rs2[t >> 6] = s2; }
    __syncthreads();
    if (t == 0) {
        float S  = rs[0] + rs[1] + rs[2] + rs[3];
        float S2 = rs2[0] + rs2[1] + rs2[2] + rs2[3];
        float m = S * invR;
        float var = fmaf(-m, m, S2 * invR);
        float scale = g[c] * rsqrtf(var + 1e-5f);
        float shift = fmaf(-m, scale, beta[c]);
        if (fold) shift += fold[256 + c];
        ss[c] = scale;
        ss[256 + c] = shift;
    }
}

// ---------------------------------------------------------------------------
// out(f32) = relu(y3(bf16) * scale + shift)
// ---------------------------------------------------------------------------
__global__ __launch_bounds__(256) void bn_relu_cvt(
    const u16* __restrict__ y3, float* __restrict__ out,
    const float* __restrict__ ss)
{
    size_t e = ((size_t)blockIdx.x * 256 + threadIdx.x) * 8;
    int kc = (int)(e & 255);
    ushort8 v = *(const ushort8*)(y3 + e);
    f32x8 sc = *(const f32x8*)(ss + kc);
    f32x8 sh = *(const f32x8*)(ss + 256 + kc);
    float4 o0, o1;
    o0.x = fmaxf(fmaf(toF((u16)v[0]), sc[0], sh[0]), 0.f);
    o0.y = fmaxf(fmaf(toF((u16)v[1]), sc[1], sh[1]), 0.f);
    o0.z = fmaxf(fmaf(toF((u16)v[2]), sc[2], sh[2]), 0.f);
    o0.w = fmaxf(fmaf(toF((u16)v[3]), sc[3], sh[3]), 0.f);
    o1.x = fmaxf(fmaf(toF((u16)v[4]), sc[4], sh[4]), 0.f);
    o1.y = fmaxf(fmaf(toF((u16)v[5]), sc[5], sh[5]), 0.f);
    o1.z = fmaxf(fmaf(toF((u16)v[6]), sc[6], sh[6]), 0.f);
    o1.w = fmaxf(fmaf(toF((u16)v[7]), sc[7], sh[7]), 0.f);
    *(float4*)(out + e) = o0;
    *(float4*)(out + e + 4) = o1;
}

// ---------------------------------------------------------------------------
// out = relu(out * scale + shift), in place (fallback when ws too small)
// ---------------------------------------------------------------------------
__global__ __launch_bounds__(256) void bn_relu_inplace(
    float* __restrict__ out, const float* __restrict__ ss)
{
    size_t i4 = (size_t)blockIdx.x * 256 + threadIdx.x;
    int c4 = (int)(i4 & 63);
    float4 v = reinterpret_cast<float4*>(out)[i4];
    float4 sc = reinterpret_cast<const float4*>(ss)[c4];
    float4 sh = reinterpret_cast<const float4*>(ss + 256)[c4];
    v.x = fmaxf(fmaf(v.x, sc.x, sh.x), 0.f);
    v.y = fmaxf(fmaf(v.y, sc.y, sh.y), 0.f);
    v.z = fmaxf(fmaf(v.z, sc.z, sh.z), 0.f);
    v.w = fmaxf(fmaf(v.w, sc.w, sh.w), 0.f);
    reinterpret_cast<float4*>(out)[i4] = v;
}

// ---------------------------------------------------------------------------
extern "C" void kernel_launch(void* const* d_in, const int* in_sizes, int n_in,
                              void* d_out, int out_size, void* d_ws, size_t ws_size,
                              hipStream_t stream) {
    const float* points1 = (const float*)d_in[0];
    const float* points2 = (const float*)d_in[1];
    const float* dist    = (const float*)d_in[2];
    const int*   idx     = (const int*)d_in[3];
    const float* Wf0     = (const float*)d_in[4];
    const float* bf0     = (const float*)d_in[5];
    const float* gf0     = (const float*)d_in[6];
    const float* betaf0  = (const float*)d_in[7];
    const float* Ws0     = (const float*)d_in[8];
    const float* bs0     = (const float*)d_in[9];
    const float* gs0     = (const float*)d_in[10];
    const float* betas0  = (const float*)d_in[11];
    const float* W1      = (const float*)d_in[12];
    const float* b1      = (const float*)d_in[13];
    const float* g1      = (const float*)d_in[14];
    const float* beta1   = (const float*)d_in[15];

    u16* ws = (u16*)d_ws;
    size_t off = 0;
    u16* y2   = ws + off;  off += (size_t)CN2 * 256;   // 32MB
    u16* xbuf = ws + off;  off += (size_t)CN1 * 256;   // 128MB
    u16* Wtf0 = ws + off;  off += 512 * 256;
    u16* Wts0 = ws + off;  off += 256 * 256;
    u16* Wt1  = ws + off;  off += 256 * 256;
    float* partial = (float*)(ws + off); off += (size_t)2048 * 512 * 2;  // 4MB
    float* ss_f0 = (float*)(ws + off); off += 1024;
    float* ss_s0 = (float*)(ws + off); off += 1024;
    float* ss_1  = (float*)(ws + off); off += 1024;
    u16* y3 = ws + off;
    const size_t NEED = (off + (size_t)CN1 * 256) * 2;   // bytes incl. bf16 y3
    const bool fused_y3 = (ws_size >= NEED);
    float* out = (float*)d_out;

    // weight transposes (f32 -> bf16, [K][256] -> [256][K]) in one launch
    transpose_all<<<1024, 256, 0, stream>>>(Wf0, Ws0, W1, Wtf0, Wts0, Wt1);

    // 1) y2 = points2 @ Wf0 + bf0   [N2 x 256] bf16, + col partials
    gemm_mfma<512, u16><<<CN2 / 128, 512, 0, stream>>>(
        points2, Wtf0, bf0, y2, partial);
    colstats_final_par<<<256, 256, 0, stream>>>(partial, CN2 / 128, 1.0f / CN2,
                                                gf0, betaf0, nullptr, ss_f0);
    // 2) skip_pre = points1 @ Ws0 + bs0   [N1 x 256] bf16, + col partials
    gemm_mfma<256, u16><<<CN1 / 128, 512, 0, stream>>>(
        points1, Wts0, bs0, xbuf, partial);
    // fold f0 shift into s0 shift (interp identity: sum w = 1)
    colstats_final_par<<<256, 256, 0, stream>>>(partial, CN1 / 128, 1.0f / CN1,
                                                gs0, betas0, ss_f0, ss_s0);
    // 3) y3 = relu(interp+skip) @ W1 + b1 (interp fused into Phase-1 staging)
    if (fused_y3) {
        gemm_fused<u16><<<CN1 / 128, 512, 0, stream>>>(
            xbuf, y2, dist, idx, ss_f0, ss_s0, Wt1, b1, y3, partial);
    } else {
        gemm_fused<float><<<CN1 / 128, 512, 0, stream>>>(
            xbuf, y2, dist, idx, ss_f0, ss_s0, Wt1, b1, out, partial);
    }
    colstats_final_par<<<256, 256, 0, stream>>>(partial, CN1 / 128, 1.0f / CN1,
                                                g1, beta1, nullptr, ss_1);
    // 4) out = relu(bn(y3))
    if (fused_y3) {
        bn_relu_cvt<<<32768, 256, 0, stream>>>(y3, out, ss_1);
    } else {
        bn_relu_inplace<<<CN1 / 4, 256, 0, stream>>>(out, ss_1);
    }
}

// Round 17
// 409.039 us; speedup vs baseline: 1.9136x; 1.0484x over previous
//
#include <hip/hip_runtime.h>
#include <hip/hip_bf16.h>

// Problem constants
#define CN1 262144
#define CN2 65536
#define CPREV 512
#define CSKIP 256

using u16 = unsigned short;

typedef __attribute__((ext_vector_type(8))) short short8;
typedef __attribute__((ext_vector_type(8))) unsigned short ushort8;
typedef __attribute__((ext_vector_type(4))) float f32x4;
typedef __attribute__((ext_vector_type(8))) float f32x8;

__device__ __forceinline__ float toF(float v) { return v; }
__device__ __forceinline__ float toF(u16 u) { return __uint_as_float(((unsigned)u) << 16); }
__device__ __forceinline__ u16 f2bf(float f) {
    unsigned b = __float_as_uint(f);
    b += 0x7FFFu + ((b >> 16) & 1u);
    return (u16)(b >> 16);
}
__device__ __forceinline__ unsigned pack2(float lo, float hi) {
    return ((unsigned)f2bf(hi) << 16) | (unsigned)f2bf(lo);
}

// ---------------------------------------------------------------------------
// All three weight transposes in one launch: Wt[n][k] (bf16) = W[k][n] (f32).
// ---------------------------------------------------------------------------
__global__ __launch_bounds__(256) void transpose_all(
    const float* __restrict__ Wf0, const float* __restrict__ Ws0,
    const float* __restrict__ W1,
    u16* __restrict__ Wtf0, u16* __restrict__ Wts0, u16* __restrict__ Wt1)
{
    int b = blockIdx.x;
    const float* W; u16* Wt; int ksh, e;
    if (b < 512)      { W = Wf0; Wt = Wtf0; ksh = 9; e = b * 256 + threadIdx.x; }
    else if (b < 768) { W = Ws0; Wt = Wts0; ksh = 8; e = (b - 512) * 256 + threadIdx.x; }
    else              { W = W1;  Wt = Wt1;  ksh = 8; e = (b - 768) * 256 + threadIdx.x; }
    int K = 1 << ksh;
    int n = e >> ksh;
    int k = e & (K - 1);
    Wt[e] = f2bf(W[((size_t)k << 8) + n]);
}

// ---------------------------------------------------------------------------
// Shared GEMM epilogue: column-stat partials from accumulators + coalesced
// C store. bf16: transpose via u16 LDS patch, 32 B/lane -> one full 128-B
// line per 4-lane group. f32: f32 patch, 32 B/lane likewise.
// ---------------------------------------------------------------------------
template<typename OT>
__device__ __forceinline__ void epilogue(
    f32x4 (&acc)[4][4], u16* AsU, u16* BsU,
    const float* __restrict__ bias, OT* __restrict__ C,
    float* __restrict__ partial, int bm, int t)
{
    const int lane = t & 63;
    const int wid = t >> 6;
    const int wrow = wid >> 2;
    const int wcol = wid & 3;
    __syncthreads();   // all fragment reads complete; LDS reusable
    float* cs  = (float*)AsU;          // [2][256] col sums
    float* cs2 = ((float*)AsU) + 512;  // [2][256] col sumsq
    const int r4 = (lane >> 4) * 4;
    const int cc = lane & 15;
    float bv[4];
#pragma unroll
    for (int ni = 0; ni < 4; ++ni) bv[ni] = bias[wcol * 64 + ni * 16 + cc];

    // column stats straight from accumulators
#pragma unroll
    for (int ni = 0; ni < 4; ++ni) {
        int col = wcol * 64 + ni * 16 + cc;
        float s = 0.f, s2 = 0.f;
#pragma unroll
        for (int mi = 0; mi < 4; ++mi) {
#pragma unroll
            for (int j = 0; j < 4; ++j) {
                float val = acc[mi][ni][j] + bv[ni];
                s += val;
                s2 = fmaf(val, val, s2);
            }
        }
        s  += __shfl_xor(s, 16);  s  += __shfl_xor(s, 32);
        s2 += __shfl_xor(s2, 16); s2 += __shfl_xor(s2, 32);
        if (lane < 16) { cs[wrow * 256 + col] = s; cs2[wrow * 256 + col] = s2; }
    }

    if constexpr (sizeof(OT) == 2) {
        // bf16 path: u16 patch [16][72] per wave (2304 B x 8 = 18432 <= Bs)
        u16* patchw = BsU + wid * (16 * 72);
        const int trow = lane >> 2;
        const int c16 = (lane & 3) * 16;
#pragma unroll
        for (int mi = 0; mi < 4; ++mi) {
            __syncthreads();
#pragma unroll
            for (int ni = 0; ni < 4; ++ni)
#pragma unroll
                for (int j = 0; j < 4; ++j)
                    patchw[(r4 + j) * 72 + ni * 16 + cc] = f2bf(acc[mi][ni][j] + bv[ni]);
            __syncthreads();
            ushort8 u0 = *(const ushort8*)&patchw[trow * 72 + c16];
            ushort8 u1 = *(const ushort8*)&patchw[trow * 72 + c16 + 8];
            size_t r = (size_t)bm + wrow * 64 + mi * 16 + trow;
            size_t cb = (size_t)wcol * 64 + c16;
            *(ushort8*)((u16*)C + r * 256 + cb) = u0;
            *(ushort8*)((u16*)C + r * 256 + cb + 8) = u1;
        }
    } else {
        // f32 path: f32 patch [16][36] per wave
        float* patchf = ((float*)BsU) + wid * (16 * 36);
        const int trow = lane >> 2;
        const int c8 = (lane & 3) * 8;
#pragma unroll
        for (int mi = 0; mi < 4; ++mi) {
#pragma unroll
            for (int np = 0; np < 2; ++np) {
                __syncthreads();
#pragma unroll
                for (int h = 0; h < 2; ++h) {
                    int ni = np * 2 + h;
#pragma unroll
                    for (int j = 0; j < 4; ++j)
                        patchf[(r4 + j) * 36 + h * 16 + cc] = acc[mi][ni][j] + bv[ni];
                }
                __syncthreads();
                float4 v0 = *(float4*)&patchf[trow * 36 + c8];
                float4 v1 = *(float4*)&patchf[trow * 36 + c8 + 4];
                size_t r = (size_t)bm + wrow * 64 + mi * 16 + trow;
                size_t cb = (size_t)wcol * 64 + np * 32 + c8;
                *(float4*)((float*)C + r * 256 + cb) = v0;
                *(float4*)((float*)C + r * 256 + cb + 4) = v1;
            }
        }
    }
    __syncthreads();
    if (t < 256) {
        partial[(size_t)blockIdx.x * 512 + t]       = cs[t] + cs[256 + t];
        partial[(size_t)blockIdx.x * 512 + 256 + t] = cs2[t] + cs2[256 + t];
    }
}

// ---------------------------------------------------------------------------
// MFMA GEMM (R9, best measured): C[M x 256] = A[M x K] @ W[K x 256] + bias.
// A f32 (converted during staging). Wt[n][k] bf16. BM=128, BN=256, BK=32.
// 512 thr / 8 waves. K compile-time; manual 2x-unrolled loop, NAMED
// double-buffer regs (no runtime-indexed arrays -> no scratch).
// ---------------------------------------------------------------------------
template<int K, typename OT>
__global__ __launch_bounds__(512) void gemm_mfma(
    const float* __restrict__ Af, const u16* __restrict__ Wt,
    const float* __restrict__ bias, OT* __restrict__ C,
    float* __restrict__ partial)
{
    __shared__ u16 As[128 * 40];
    __shared__ u16 Bs[256 * 40];
    const int t = threadIdx.x;
    const int bm = blockIdx.x * 128;
    const int lane = t & 63;
    const int wid = t >> 6;
    const int wrow = wid >> 2;
    const int wcol = wid & 3;

    const int arow = t >> 2;       // 0..127
    const int koff = (t & 3) * 8;  // 0,8,16,24

    f32x4 acc[4][4] = {};

    float4 ga0A, ga1A, ga0B, ga1B;
    ushort8 gb0A, gb1A, gb0B, gb1B;

    auto LOADA = [&](int k0) {
        const float* p = Af + (size_t)(bm + arow) * K + k0 + koff;
        ga0A = *(const float4*)p;
        ga1A = *(const float4*)(p + 4);
        const u16* q = Wt + (size_t)arow * K + k0 + koff;
        gb0A = *(const ushort8*)q;
        gb1A = *(const ushort8*)(q + (size_t)128 * K);
    };
    auto LOADB = [&](int k0) {
        const float* p = Af + (size_t)(bm + arow) * K + k0 + koff;
        ga0B = *(const float4*)p;
        ga1B = *(const float4*)(p + 4);
        const u16* q = Wt + (size_t)arow * K + k0 + koff;
        gb0B = *(const ushort8*)q;
        gb1B = *(const ushort8*)(q + (size_t)128 * K);
    };
    auto STAGE = [&](const float4& g0, const float4& g1,
                     const ushort8& b0, const ushort8& b1) {
        uint4 w;
        w.x = pack2(g0.x, g0.y);
        w.y = pack2(g0.z, g0.w);
        w.z = pack2(g1.x, g1.y);
        w.w = pack2(g1.z, g1.w);
        *(uint4*)&As[arow * 40 + koff] = w;
        *(ushort8*)&Bs[arow * 40 + koff] = b0;
        *(ushort8*)&Bs[(128 + arow) * 40 + koff] = b1;
    };
    auto MMA = [&]() {
        const int kq = (lane >> 4) * 8;
        const int rr = lane & 15;
        short8 af[4];
#pragma unroll
        for (int mi = 0; mi < 4; ++mi)
            af[mi] = *(const short8*)&As[(wrow * 64 + mi * 16 + rr) * 40 + kq];
#pragma unroll
        for (int ni = 0; ni < 4; ++ni) {
            short8 bf = *(const short8*)&Bs[(wcol * 64 + ni * 16 + rr) * 40 + kq];
#pragma unroll
            for (int mi = 0; mi < 4; ++mi)
                acc[mi][ni] = __builtin_amdgcn_mfma_f32_16x16x32_bf16(
                    af[mi], bf, acc[mi][ni], 0, 0, 0);
        }
    };

    constexpr int nk = K >> 5;   // even (16 or 8)
    LOADA(0);
    LOADB(32);
#pragma unroll
    for (int it = 0; it < nk; it += 2) {
        __syncthreads();
        STAGE(ga0A, ga1A, gb0A, gb1A);
        __syncthreads();
        if (it + 2 < nk) LOADA((it + 2) << 5);
        MMA();
        __syncthreads();
        STAGE(ga0B, ga1B, gb0B, gb1B);
        __syncthreads();
        if (it + 3 < nk) LOADB((it + 3) << 5);
        MMA();
    }

    epilogue<OT>(acc, As, Bs, bias, C, partial, bm, t);
}

// ---------------------------------------------------------------------------
// Fused GEMM for layer 1 (R9, best measured): A-staging computes
//   x[row][k] = relu( interp(y2)*sf + skip*sx + csh )  on the fly.
// K=256. Named double-buffer regs; scale/shift tables in LDS.
// ---------------------------------------------------------------------------
template<typename OT>
__global__ __launch_bounds__(512) void gemm_fused(
    const u16* __restrict__ skipb, const u16* __restrict__ y2,
    const float* __restrict__ dist, const int* __restrict__ idx,
    const float* __restrict__ ssf, const float* __restrict__ sss,
    const u16* __restrict__ Wt, const float* __restrict__ bias,
    OT* __restrict__ C, float* __restrict__ partial)
{
    constexpr int K = 256;
    __shared__ u16 As[128 * 40];
    __shared__ u16 Bs[256 * 40];
    __shared__ float sstab[768];   // scale_f0 | scale_s0 | shift(folded)
    const int t = threadIdx.x;
    const int bm = blockIdx.x * 128;
    const int lane = t & 63;
    const int wid = t >> 6;
    const int wrow = wid >> 2;
    const int wcol = wid & 3;

    const int arow = t >> 2;       // 0..127
    const int koff = (t & 3) * 8;  // 0,8,16,24
    const int row = bm + arow;

    for (int e = t; e < 768; e += 512)
        sstab[e] = (e < 256) ? ssf[e] : sss[e - 256];

    float d0 = dist[row * 3 + 0], d1 = dist[row * 3 + 1], d2 = dist[row * 3 + 2];
    float r0 = 1.f / (d0 + 1e-8f), r1 = 1.f / (d1 + 1e-8f), r2 = 1.f / (d2 + 1e-8f);
    float inv = 1.f / (r0 + r1 + r2);
    const float w0 = r0 * inv, w1 = r1 * inv, w2 = r2 * inv;
    const size_t i0 = (size_t)(unsigned)idx[row * 3 + 0];
    const size_t i1 = (size_t)(unsigned)idx[row * 3 + 1];
    const size_t i2 = (size_t)(unsigned)idx[row * 3 + 2];

    f32x4 acc[4][4] = {};

    ushort8 skA, a0A, a1A, a2A, gb0A, gb1A;
    ushort8 skB, a0B, a1B, a2B, gb0B, gb1B;

    auto LOADA = [&](int k0) {
        const int kc = k0 + koff;
        skA = *(const ushort8*)(skipb + (size_t)row * 256 + kc);
        a0A = *(const ushort8*)(y2 + i0 * 256 + kc);
        a1A = *(const ushort8*)(y2 + i1 * 256 + kc);
        a2A = *(const ushort8*)(y2 + i2 * 256 + kc);
        const u16* q = Wt + (size_t)arow * K + kc;
        gb0A = *(const ushort8*)q;
        gb1A = *(const ushort8*)(q + (size_t)128 * K);
    };
    auto LOADB = [&](int k0) {
        const int kc = k0 + koff;
        skB = *(const ushort8*)(skipb + (size_t)row * 256 + kc);
        a0B = *(const ushort8*)(y2 + i0 * 256 + kc);
        a1B = *(const ushort8*)(y2 + i1 * 256 + kc);
        a2B = *(const ushort8*)(y2 + i2 * 256 + kc);
        const u16* q = Wt + (size_t)arow * K + kc;
        gb0B = *(const ushort8*)q;
        gb1B = *(const ushort8*)(q + (size_t)128 * K);
    };
    auto STAGE = [&](int it, const ushort8& sk8, const ushort8& a0,
                     const ushort8& a1, const ushort8& a2,
                     const ushort8& b0, const ushort8& b1) {
        const int kc = (it << 5) + koff;
        f32x8 sf = *(const f32x8*)&sstab[kc];
        f32x8 sx = *(const f32x8*)&sstab[256 + kc];
        f32x8 ch = *(const f32x8*)&sstab[512 + kc];
        float xs[8];
#pragma unroll
        for (int j = 0; j < 8; ++j) {
            float iv = w0 * toF((u16)a0[j]) + w1 * toF((u16)a1[j])
                     + w2 * toF((u16)a2[j]);
            float val = fmaf(iv, sf[j], fmaf(toF((u16)sk8[j]), sx[j], ch[j]));
            xs[j] = fmaxf(val, 0.f);
        }
        uint4 w;
        w.x = pack2(xs[0], xs[1]);
        w.y = pack2(xs[2], xs[3]);
        w.z = pack2(xs[4], xs[5]);
        w.w = pack2(xs[6], xs[7]);
        *(uint4*)&As[arow * 40 + koff] = w;
        *(ushort8*)&Bs[arow * 40 + koff] = b0;
        *(ushort8*)&Bs[(128 + arow) * 40 + koff] = b1;
    };
    auto MMA = [&]() {
        const int kq = (lane >> 4) * 8;
        const int rr = lane & 15;
        short8 af[4];
#pragma unroll
        for (int mi = 0; mi < 4; ++mi)
            af[mi] = *(const short8*)&As[(wrow * 64 + mi * 16 + rr) * 40 + kq];
#pragma unroll
        for (int ni = 0; ni < 4; ++ni) {
            short8 bf = *(const short8*)&Bs[(wcol * 64 + ni * 16 + rr) * 40 + kq];
#pragma unroll
            for (int mi = 0; mi < 4; ++mi)
                acc[mi][ni] = __builtin_amdgcn_mfma_f32_16x16x32_bf16(
                    af[mi], bf, acc[mi][ni], 0, 0, 0);
        }
    };

    constexpr int nk = K >> 5;   // 8
    LOADA(0);
    LOADB(32);
#pragma unroll
    for (int it = 0; it < nk; it += 2) {
        __syncthreads();
        STAGE(it, skA, a0A, a1A, a2A, gb0A, gb1A);
        __syncthreads();
        if (it + 2 < nk) LOADA((it + 2) << 5);
        MMA();
        __syncthreads();
        STAGE(it + 1, skB, a0B, a1B, a2B, gb0B, gb1B);
        __syncthreads();
        if (it + 3 < nk) LOADB((it + 3) << 5);
        MMA();
    }

    epilogue<OT>(acc, As, Bs, bias, C, partial, bm, t);
}

// ---------------------------------------------------------------------------
// Stats finalize: one block per column; optional shift folding.
// ---------------------------------------------------------------------------
__global__ __launch_bounds__(256) void colstats_final_par(
    const float* __restrict__ partial, int nb, float invR,
    const float* __restrict__ g, const float* __restrict__ beta,
    const float* __restrict__ fold, float* __restrict__ ss)
{
    int c = blockIdx.x;
    int t = threadIdx.x;
    float s = 0.f, s2 = 0.f;
    for (int b = t; b < nb; b += 256) {
        s  += partial[(size_t)b * 512 + c];
        s2 += partial[(size_t)b * 512 + 256 + c];
    }
#pragma unroll
    for (int o = 32; o > 0; o >>= 1) {
        s += __shfl_xor(s, o);
        s2 += __shfl_xor(s2, o);
    }
    __shared__ float rs[4], rs2[4];
    if ((t & 63) == 0) { rs[t >> 6] = s; rs2[t >> 6] = s2; }
    __syncthreads();
    if (t == 0) {
        float S  = rs[0] + rs[1] + rs[2] + rs[3];
        float S2 = rs2[0] + rs2[1] + rs2[2] + rs2[3];
        float m = S * invR;
        float var = fmaf(-m, m, S2 * invR);
        float scale = g[c] * rsqrtf(var + 1e-5f);
        float shift = fmaf(-m, scale, beta[c]);
        if (fold) shift += fold[256 + c];
        ss[c] = scale;
        ss[256 + c] = shift;
    }
}

// ---------------------------------------------------------------------------
// out(f32) = relu(y3(bf16) * scale + shift)
// ---------------------------------------------------------------------------
__global__ __launch_bounds__(256) void bn_relu_cvt(
    const u16* __restrict__ y3, float* __restrict__ out,
    const float* __restrict__ ss)
{
    size_t e = ((size_t)blockIdx.x * 256 + threadIdx.x) * 8;
    int kc = (int)(e & 255);
    ushort8 v = *(const ushort8*)(y3 + e);
    f32x8 sc = *(const f32x8*)(ss + kc);
    f32x8 sh = *(const f32x8*)(ss + 256 + kc);
    float4 o0, o1;
    o0.x = fmaxf(fmaf(toF((u16)v[0]), sc[0], sh[0]), 0.f);
    o0.y = fmaxf(fmaf(toF((u16)v[1]), sc[1], sh[1]), 0.f);
    o0.z = fmaxf(fmaf(toF((u16)v[2]), sc[2], sh[2]), 0.f);
    o0.w = fmaxf(fmaf(toF((u16)v[3]), sc[3], sh[3]), 0.f);
    o1.x = fmaxf(fmaf(toF((u16)v[4]), sc[4], sh[4]), 0.f);
    o1.y = fmaxf(fmaf(toF((u16)v[5]), sc[5], sh[5]), 0.f);
    o1.z = fmaxf(fmaf(toF((u16)v[6]), sc[6], sh[6]), 0.f);
    o1.w = fmaxf(fmaf(toF((u16)v[7]), sc[7], sh[7]), 0.f);
    *(float4*)(out + e) = o0;
    *(float4*)(out + e + 4) = o1;
}

// ---------------------------------------------------------------------------
// out = relu(out * scale + shift), in place (fallback when ws too small)
// ---------------------------------------------------------------------------
__global__ __launch_bounds__(256) void bn_relu_inplace(
    float* __restrict__ out, const float* __restrict__ ss)
{
    size_t i4 = (size_t)blockIdx.x * 256 + threadIdx.x;
    int c4 = (int)(i4 & 63);
    float4 v = reinterpret_cast<float4*>(out)[i4];
    float4 sc = reinterpret_cast<const float4*>(ss)[c4];
    float4 sh = reinterpret_cast<const float4*>(ss + 256)[c4];
    v.x = fmaxf(fmaf(v.x, sc.x, sh.x), 0.f);
    v.y = fmaxf(fmaf(v.y, sc.y, sh.y), 0.f);
    v.z = fmaxf(fmaf(v.z, sc.z, sh.z), 0.f);
    v.w = fmaxf(fmaf(v.w, sc.w, sh.w), 0.f);
    reinterpret_cast<float4*>(out)[i4] = v;
}

// ---------------------------------------------------------------------------
extern "C" void kernel_launch(void* const* d_in, const int* in_sizes, int n_in,
                              void* d_out, int out_size, void* d_ws, size_t ws_size,
                              hipStream_t stream) {
    const float* points1 = (const float*)d_in[0];
    const float* points2 = (const float*)d_in[1];
    const float* dist    = (const float*)d_in[2];
    const int*   idx     = (const int*)d_in[3];
    const float* Wf0     = (const float*)d_in[4];
    const float* bf0     = (const float*)d_in[5];
    const float* gf0     = (const float*)d_in[6];
    const float* betaf0  = (const float*)d_in[7];
    const float* Ws0     = (const float*)d_in[8];
    const float* bs0     = (const float*)d_in[9];
    const float* gs0     = (const float*)d_in[10];
    const float* betas0  = (const float*)d_in[11];
    const float* W1      = (const float*)d_in[12];
    const float* b1      = (const float*)d_in[13];
    const float* g1      = (const float*)d_in[14];
    const float* beta1   = (const float*)d_in[15];

    u16* ws = (u16*)d_ws;
    size_t off = 0;
    u16* y2   = ws + off;  off += (size_t)CN2 * 256;   // 32MB
    u16* xbuf = ws + off;  off += (size_t)CN1 * 256;   // 128MB
    u16* Wtf0 = ws + off;  off += 512 * 256;
    u16* Wts0 = ws + off;  off += 256 * 256;
    u16* Wt1  = ws + off;  off += 256 * 256;
    float* partial = (float*)(ws + off); off += (size_t)2048 * 512 * 2;  // 4MB
    float* ss_f0 = (float*)(ws + off); off += 1024;
    float* ss_s0 = (float*)(ws + off); off += 1024;
    float* ss_1  = (float*)(ws + off); off += 1024;
    u16* y3 = ws + off;
    const size_t NEED = (off + (size_t)CN1 * 256) * 2;   // bytes incl. bf16 y3
    const bool fused_y3 = (ws_size >= NEED);
    float* out = (float*)d_out;

    // weight transposes (f32 -> bf16, [K][256] -> [256][K]) in one launch
    transpose_all<<<1024, 256, 0, stream>>>(Wf0, Ws0, W1, Wtf0, Wts0, Wt1);

    // 1) y2 = points2 @ Wf0 + bf0   [N2 x 256] bf16, + col partials
    gemm_mfma<512, u16><<<CN2 / 128, 512, 0, stream>>>(
        points2, Wtf0, bf0, y2, partial);
    colstats_final_par<<<256, 256, 0, stream>>>(partial, CN2 / 128, 1.0f / CN2,
                                                gf0, betaf0, nullptr, ss_f0);
    // 2) skip_pre = points1 @ Ws0 + bs0   [N1 x 256] bf16, + col partials
    gemm_mfma<256, u16><<<CN1 / 128, 512, 0, stream>>>(
        points1, Wts0, bs0, xbuf, partial);
    // fold f0 shift into s0 shift (interp identity: sum w = 1)
    colstats_final_par<<<256, 256, 0, stream>>>(partial, CN1 / 128, 1.0f / CN1,
                                                gs0, betas0, ss_f0, ss_s0);
    // 3) y3 = relu(interp+skip) @ W1 + b1 (interp fused into staging)
    if (fused_y3) {
        gemm_fused<u16><<<CN1 / 128, 512, 0, stream>>>(
            xbuf, y2, dist, idx, ss_f0, ss_s0, Wt1, b1, y3, partial);
    } else {
        gemm_fused<float><<<CN1 / 128, 512, 0, stream>>>(
            xbuf, y2, dist, idx, ss_f0, ss_s0, Wt1, b1, out, partial);
    }
    colstats_final_par<<<256, 256, 0, stream>>>(partial, CN1 / 128, 1.0f / CN1,
                                                g1, beta1, nullptr, ss_1);
    // 4) out = relu(bn(y3))
    if (fused_y3) {
        bn_relu_cvt<<<32768, 256, 0, stream>>>(y3, out, ss_1);
    } else {
        bn_relu_inplace<<<CN1 / 4, 256, 0, stream>>>(out, ss_1);
    }
}